// Round 6
// baseline (232.884 us; speedup 1.0000x reference)
//
#include <hip/hip_runtime.h>
#include <math.h>

#define B_ 32
#define NODES_ 512
#define IN_ 256
#define OUT_ 128
#define CAPS_ 16
#define KW_ 5
#define M_ (B_*NODES_)            // 16384
#define N_ (KW_*OUT_)             // 640

typedef __attribute__((ext_vector_type(8))) short short8;
typedef __attribute__((ext_vector_type(4))) float f32x4;

// ---- workspace layout (bytes) ----
// common: y f32 [16384][640] @0 ; logits @41,943,040 ; v @42,991,616 ; s_part @43,253,760
#define Y_BOFF   0
#define L_BOFF   41943040
#define V_BOFF   42991616
#define SP_BOFF  43253760
#define BT_SZ    (N_*IN_*2)            // 327,680 bytes per bT matrix
// BIG path (ws >= 60,030,976): s_part has 64 chunks (16.78 MB);
//   xhi/xlo alias s_part region; bThi/bTlo alias logits region.
#define SP64_SZ  (B_*64*CAPS_*OUT_*4)  // 16,777,216
#define WS_NEED_BIG (SP_BOFF + SP64_SZ)
#define XSP_SZ   (M_*IN_*2)            // 8,388,608
// SMALL path (round-5 proven): s_part 32 chunks; bT aliases s_part region.

__device__ __forceinline__ float b2f(unsigned short u) {
  union { unsigned int i; float f; } c; c.i = ((unsigned int)u) << 16; return c.f;
}
__device__ __forceinline__ unsigned short f2b(float f) {
  union { float f; unsigned int i; } c; c.f = f;
  unsigned int u = c.i;
  u += 0x7fffu + ((u >> 16) & 1u);
  return (unsigned short)(u >> 16);
}
__device__ __forceinline__ void async_load16(const void* g, void* l) {
  __builtin_amdgcn_global_load_lds(
      (const __attribute__((address_space(1))) unsigned int*)g,
      (__attribute__((address_space(3))) unsigned int*)l, 16, 0, 0);
}

// ============================================================
// conv_x: split x f32 -> xhi/xlo bf16
// ============================================================
__global__ __launch_bounds__(256) void conv_x(const float* __restrict__ x,
                                              unsigned short* __restrict__ xhi,
                                              unsigned short* __restrict__ xlo) {
  int idx = blockIdx.x*256 + threadIdx.x;     // 4 floats each, 4.19M total
  float4 v = *(const float4*)(x + (size_t)idx*4);
  ushort4 h, l;
  h.x = f2b(v.x); l.x = f2b(v.x - b2f(h.x));
  h.y = f2b(v.y); l.y = f2b(v.y - b2f(h.y));
  h.z = f2b(v.z); l.z = f2b(v.z - b2f(h.z));
  h.w = f2b(v.w); l.w = f2b(v.w - b2f(h.w));
  *(ushort4*)(xhi + (size_t)idx*4) = h;
  *(ushort4*)(xlo + (size_t)idx*4) = l;
}

// ============================================================
// conv_w: split W into bThi/bTlo: bT*[n=k*128+o][i] = W[k][i][o]
// ============================================================
__global__ __launch_bounds__(256) void conv_w(const float* __restrict__ W,
                                              unsigned short* __restrict__ bThi,
                                              unsigned short* __restrict__ bTlo) {
  int n = blockIdx.x;           // 0..639
  int i = threadIdx.x;          // 0..255
  int k = n >> 7, o = n & 127;
  float v = W[((size_t)k*IN_ + i)*OUT_ + o];
  unsigned short h = f2b(v);
  bThi[(size_t)n*IN_ + i] = h;
  bTlo[(size_t)n*IN_ + i] = f2b(v - b2f(h));
}

// ============================================================
// gemm_bf4 (BIG): y = x @ bT^T via split-bf16 (hi*hi+hi*lo+lo*hi).
// Tile 64x128, BK=32, 4 waves 2x2 (wave tile 32x64), pure-bf16 LDS.
// ============================================================
__global__ __launch_bounds__(256, 4) void gemm_bf4(const unsigned short* __restrict__ xhi,
                                                   const unsigned short* __restrict__ xlo,
                                                   const unsigned short* __restrict__ bThi,
                                                   const unsigned short* __restrict__ bTlo,
                                                   float* __restrict__ y) {
  __shared__ short Ah_lds[4*64*8];    // 4 KB  [cg][row][8]
  __shared__ short Al_lds[4*64*8];    // 4 KB
  __shared__ short Bh_lds[4*128*8];   // 8 KB
  __shared__ short Bl_lds[4*128*8];   // 8 KB
  const int t    = threadIdx.x;
  const int lane = t & 63;
  const int w    = t >> 6;
  const int wm   = w >> 1;          // 0..1 (32-row half)
  const int wn   = w & 1;           // 0..1 (64-col half)
  const int m0   = blockIdx.x * 64;
  const int n0   = blockIdx.y * 128;
  const int lrow = lane & 15;
  const int lk   = lane >> 4;       // 0..3

  f32x4 acc[2][4];
  #pragma unroll
  for (int i=0;i<2;++i)
    #pragma unroll
    for (int j=0;j<4;++j) acc[i][j] = (f32x4){0.f,0.f,0.f,0.f};

  const int cgA = t >> 6, rA = t & 63;        // A: 256 chunks
  for (int kb = 0; kb < IN_; kb += 32) {
    async_load16(xhi + (size_t)(m0 + rA)*IN_ + kb + cgA*8, &Ah_lds[t*8]);
    async_load16(xlo + (size_t)(m0 + rA)*IN_ + kb + cgA*8, &Al_lds[t*8]);
    #pragma unroll
    for (int q=0; q<2; ++q) {                 // B: 512 chunks each
      int d  = q*256 + t;
      int cg = d >> 7, r = d & 127;
      async_load16(bThi + (size_t)(n0 + r)*IN_ + kb + cg*8, &Bh_lds[d*8]);
      async_load16(bTlo + (size_t)(n0 + r)*IN_ + kb + cg*8, &Bl_lds[d*8]);
    }
    __syncthreads();

    short8 ah[2], al[2], bh[4], bl[4];
    #pragma unroll
    for (int mi=0; mi<2; ++mi) {
      int row_a = wm*32 + mi*16 + lrow;
      ah[mi] = *(const short8*)&Ah_lds[(lk*64 + row_a)*8];
      al[mi] = *(const short8*)&Al_lds[(lk*64 + row_a)*8];
    }
    #pragma unroll
    for (int ni=0; ni<4; ++ni) {
      int row_b = wn*64 + ni*16 + lrow;
      bh[ni] = *(const short8*)&Bh_lds[(lk*128 + row_b)*8];
      bl[ni] = *(const short8*)&Bl_lds[(lk*128 + row_b)*8];
    }
    #pragma unroll
    for (int mi=0; mi<2; ++mi)
      #pragma unroll
      for (int ni=0; ni<4; ++ni) {
        acc[mi][ni] = __builtin_amdgcn_mfma_f32_16x16x32_bf16(bh[ni], ah[mi], acc[mi][ni], 0, 0, 0);
        acc[mi][ni] = __builtin_amdgcn_mfma_f32_16x16x32_bf16(bh[ni], al[mi], acc[mi][ni], 0, 0, 0);
        acc[mi][ni] = __builtin_amdgcn_mfma_f32_16x16x32_bf16(bl[ni], ah[mi], acc[mi][ni], 0, 0, 0);
      }
    __syncthreads();
  }

  #pragma unroll
  for (int mi=0; mi<2; ++mi) {
    int m = m0 + wm*32 + mi*16 + lrow;
    #pragma unroll
    for (int ni=0; ni<4; ++ni) {
      int nb = n0 + wn*64 + ni*16 + lk*4;
      float4 o = {acc[mi][ni][0], acc[mi][ni][1], acc[mi][ni][2], acc[mi][ni][3]};
      *(float4*)(y + (size_t)m*N_ + nb) = o;
    }
  }
}

// ============================================================
// gemm_insplit (SMALL fallback = round-5 proven kernel)
// ============================================================
__global__ __launch_bounds__(256) void gemm_insplit(const float* __restrict__ x,
                                                    const unsigned short* __restrict__ bThi,
                                                    const unsigned short* __restrict__ bTlo,
                                                    float* __restrict__ y) {
  __shared__ float A_lds[8*128*4];
  __shared__ short Bh_lds[4*128*8];
  __shared__ short Bl_lds[4*128*8];
  const int t    = threadIdx.x;
  const int w    = t >> 6;
  const int lane = t & 63;
  const int wm   = w >> 1;
  const int wn   = w & 1;
  const int m0   = blockIdx.x * 128;
  const int n0   = blockIdx.y * 128;
  const int lrow = lane & 15;
  const int lk   = lane >> 4;

  f32x4 acc[4][4];
  #pragma unroll
  for (int i=0;i<4;++i)
    #pragma unroll
    for (int j=0;j<4;++j) acc[i][j] = (f32x4){0.f,0.f,0.f,0.f};

  for (int kb = 0; kb < IN_; kb += 32) {
    #pragma unroll
    for (int q=0; q<4; ++q) {
      int d0 = q*256 + w*64;
      int d  = d0 + lane;
      int cg = d >> 7;
      int r  = d & 127;
      async_load16(x + (size_t)(m0 + r)*IN_ + kb + cg*4, &A_lds[d0*4]);
    }
    #pragma unroll
    for (int q=0; q<2; ++q) {
      int d0 = q*256 + w*64;
      int d  = d0 + lane;
      int cg = d >> 7;
      int r  = d & 127;
      async_load16(bThi + (size_t)(n0 + r)*IN_ + kb + cg*8, &Bh_lds[d0*8]);
      async_load16(bTlo + (size_t)(n0 + r)*IN_ + kb + cg*8, &Bl_lds[d0*8]);
    }
    __syncthreads();

    short8 ah[4], al[4], bh[4], bl[4];
    #pragma unroll
    for (int mi=0; mi<4; ++mi) {
      int row_a = wm*64 + mi*16 + lrow;
      f32x4 a0 = *(const f32x4*)&A_lds[((2*lk  )*128 + row_a)*4];
      f32x4 a1 = *(const f32x4*)&A_lds[((2*lk+1)*128 + row_a)*4];
      #pragma unroll
      for (int j=0; j<8; ++j) {
        float f = (j < 4) ? a0[j] : a1[j-4];
        unsigned short h = f2b(f);
        ah[mi][j] = (short)h;
        al[mi][j] = (short)f2b(f - b2f(h));
      }
    }
    #pragma unroll
    for (int ni=0; ni<4; ++ni) {
      int row_b = wn*64 + ni*16 + lrow;
      bh[ni] = *(const short8*)&Bh_lds[(lk*128 + row_b)*8];
      bl[ni] = *(const short8*)&Bl_lds[(lk*128 + row_b)*8];
    }
    #pragma unroll
    for (int mi=0; mi<4; ++mi)
      #pragma unroll
      for (int ni=0; ni<4; ++ni) {
        acc[mi][ni] = __builtin_amdgcn_mfma_f32_16x16x32_bf16(bh[ni], ah[mi], acc[mi][ni], 0, 0, 0);
        acc[mi][ni] = __builtin_amdgcn_mfma_f32_16x16x32_bf16(bh[ni], al[mi], acc[mi][ni], 0, 0, 0);
        acc[mi][ni] = __builtin_amdgcn_mfma_f32_16x16x32_bf16(bl[ni], ah[mi], acc[mi][ni], 0, 0, 0);
      }
    __syncthreads();
  }

  #pragma unroll
  for (int mi=0; mi<4; ++mi) {
    int m = m0 + wm*64 + mi*16 + lrow;
    #pragma unroll
    for (int ni=0; ni<4; ++ni) {
      int nb = n0 + wn*64 + ni*16 + lk*4;
      float4 o = {acc[mi][ni][0], acc[mi][ni][1], acc[mi][ni][2], acc[mi][ni][3]};
      *(float4*)(y + (size_t)m*N_ + nb) = o;
    }
  }
}

// ============================================================
// route_step8 (BIG): 8-node chunks, 64 chunks, LDS ~33 KB.
// ============================================================
__global__ __launch_bounds__(256) void route_step8(const float* __restrict__ y,
                                                   const float* __restrict__ alpha,
                                                   const float* __restrict__ contrib,
                                                   float* __restrict__ logits,
                                                   const float* __restrict__ vin,
                                                   float* __restrict__ s_part,
                                                   int mode) {
  __shared__ __align__(16) float sh_y[8*644];       // 20.6 KB
  __shared__ __align__(16) float sh_v[16*132];      //  8.4 KB
  __shared__ __align__(16) float sh_alpha[8*16*5];  //  2.6 KB
  __shared__ float sh_logit[8][16];
  __shared__ float sh_cw[8][16];

  const int t  = threadIdx.x;
  const int ch = blockIdx.x;   // 0..63
  const int b  = blockIdx.y;   // 0..31
  const int n0 = ch*8;

  // stage y: 8 nodes x 640 f32 = 1280 float4
  const float* ybase = y + ((size_t)(b*NODES_ + n0))*KW_*OUT_;
  #pragma unroll
  for (int q=0; q<5; ++q) {
    int idx4 = t + q*256;
    int flat = idx4*4;
    int node = flat / 640;
    int rem  = flat - node*640;
    float4 vv = *(const float4*)(ybase + flat);
    *(float4*)&sh_y[node*644 + rem] = vv;
  }
  // alpha: 8 x 80 f = 160 float4
  const float* abase = alpha + (size_t)n0*CAPS_*KW_;
  if (t < 160) {
    float4 av = *(const float4*)(abase + t*4);
    *(float4*)&sh_alpha[t*4] = av;
  }
  if (mode >= 1) {
    const float* vbase = vin + (size_t)b*CAPS_*OUT_;
    #pragma unroll
    for (int q=0; q<2; ++q) {
      int flat = (t + q*256)*4;
      int c = flat >> 7, o = flat & 127;
      float4 vv = *(const float4*)(vbase + flat);
      *(float4*)&sh_v[c*132 + o] = vv;
    }
    if (t < 128) {
      int node = t & 7, cap = t >> 3;
      sh_logit[node][cap] = logits[((size_t)b*CAPS_ + cap)*NODES_ + n0 + node];
    }
  } else {
    if (t < 128) {
      int node = t & 7, cap = t >> 3;
      float cv = contrib[(size_t)b*NODES_ + n0 + node];
      sh_logit[node][cap] = cv;
      logits[((size_t)b*CAPS_ + cap)*NODES_ + n0 + node] = cv;
    }
  }
  __syncthreads();

  if (mode >= 1) {
    // phase 1: 8 nodes x 16 caps x 2 o-halves
    int node = t >> 5, cap = (t >> 1) & 15, half = t & 1;
    const float* al = &sh_alpha[(node*16+cap)*5];
    float a0=al[0],a1=al[1],a2=al[2],a3=al[3],a4=al[4];
    const float* yb = &sh_y[node*644] + half*64;
    const float* vb = &sh_v[cap*132]  + half*64;
    float accd = 0.f;
    #pragma unroll 4
    for (int o=0; o<64; o+=4) {
      float4 y0 = *(const float4*)(yb + 0*128 + o);
      float4 y1 = *(const float4*)(yb + 1*128 + o);
      float4 y2 = *(const float4*)(yb + 2*128 + o);
      float4 y3 = *(const float4*)(yb + 3*128 + o);
      float4 y4 = *(const float4*)(yb + 4*128 + o);
      float4 vv = *(const float4*)(vb + o);
      float ux = a0*y0.x + a1*y1.x + a2*y2.x + a3*y3.x + a4*y4.x;
      float uy = a0*y0.y + a1*y1.y + a2*y2.y + a3*y3.y + a4*y4.y;
      float uz = a0*y0.z + a1*y1.z + a2*y2.z + a3*y3.z + a4*y4.z;
      float uw = a0*y0.w + a1*y1.w + a2*y2.w + a3*y3.w + a4*y4.w;
      accd += ux*vv.x + uy*vv.y + uz*vv.z + uw*vv.w;
    }
    float tot = accd + __shfl_xor(accd, 1, 64);
    if (half == 0) {
      float newl = sh_logit[node][cap] + tot;
      sh_logit[node][cap] = newl;
      logits[((size_t)b*CAPS_ + cap)*NODES_ + n0 + node] = newl;
    }
    __syncthreads();
    if (t < 8) {
      int nd = t;
      float m = -1e30f;
      #pragma unroll
      for (int c=0;c<16;++c) m = fmaxf(m, sh_logit[nd][c]);
      float s = 0.f;
      float e[16];
      #pragma unroll
      for (int c=0;c<16;++c) { e[c] = __expf(sh_logit[nd][c]-m); s += e[c]; }
      float inv = 1.f/s;
      #pragma unroll
      for (int c=0;c<16;++c) sh_cw[nd][c] = e[c]*inv;
    }
  } else {
    if (t < 128) sh_cw[t & 7][t >> 3] = 1.f/16.f;
  }
  __syncthreads();

  // phase 2: c = t>>4, o0 = (t&15)*8, sum over 8 nodes
  {
    int c  = t >> 4;
    int o0 = (t & 15)*8;
    float acc[8] = {0,0,0,0,0,0,0,0};
    #pragma unroll 2
    for (int nd=0; nd<8; ++nd) {
      const float* al = &sh_alpha[(nd*16+c)*5];
      float a0=al[0],a1=al[1],a2=al[2],a3=al[3],a4=al[4];
      float cw = sh_cw[nd][c];
      const float* yb = &sh_y[nd*644 + o0];
      #pragma unroll
      for (int h=0; h<2; ++h) {
        float4 y0 = *(const float4*)(yb + h*4);
        float4 y1 = *(const float4*)(yb + 128 + h*4);
        float4 y2 = *(const float4*)(yb + 256 + h*4);
        float4 y3 = *(const float4*)(yb + 384 + h*4);
        float4 y4 = *(const float4*)(yb + 512 + h*4);
        acc[h*4+0] += cw*(a0*y0.x + a1*y1.x + a2*y2.x + a3*y3.x + a4*y4.x);
        acc[h*4+1] += cw*(a0*y0.y + a1*y1.y + a2*y2.y + a3*y3.y + a4*y4.y);
        acc[h*4+2] += cw*(a0*y0.z + a1*y1.z + a2*y2.z + a3*y3.z + a4*y4.z);
        acc[h*4+3] += cw*(a0*y0.w + a1*y1.w + a2*y2.w + a3*y3.w + a4*y4.w);
      }
    }
    float* spb = s_part + ((size_t)(b*64 + ch)*CAPS_ + c)*OUT_ + o0;
    float4 w0 = {acc[0],acc[1],acc[2],acc[3]};
    float4 w1 = {acc[4],acc[5],acc[6],acc[7]};
    *(float4*)(spb)     = w0;
    *(float4*)(spb + 4) = w1;
  }
}

// ============================================================
// route_step16 (SMALL fallback = round-5 proven kernel)
// ============================================================
__global__ __launch_bounds__(256) void route_step16(const float* __restrict__ y,
                                                    const float* __restrict__ alpha,
                                                    const float* __restrict__ contrib,
                                                    float* __restrict__ logits,
                                                    const float* __restrict__ vin,
                                                    float* __restrict__ s_part,
                                                    int mode) {
  __shared__ __align__(16) float sh_y[16*644];
  __shared__ __align__(16) float sh_v[16*132];
  __shared__ __align__(16) float sh_alpha[16*16*5];
  __shared__ float sh_logit[16][16];
  __shared__ float sh_cw[16][16];

  const int t  = threadIdx.x;
  const int ch = blockIdx.x;
  const int b  = blockIdx.y;
  const int n0 = ch*16;

  const float* ybase = y + ((size_t)(b*NODES_ + n0))*KW_*OUT_;
  #pragma unroll
  for (int q=0; q<10; ++q) {
    int idx4 = t + q*256;
    int flat = idx4*4;
    int node = flat / 640;
    int rem  = flat - node*640;
    float4 vv = *(const float4*)(ybase + flat);
    *(float4*)&sh_y[node*644 + rem] = vv;
  }
  const float* abase = alpha + (size_t)n0*CAPS_*KW_;
  for (int i = t; i < 320; i += 256) {
    float4 av = *(const float4*)(abase + i*4);
    *(float4*)&sh_alpha[i*4] = av;
  }
  if (mode >= 1) {
    const float* vbase = vin + (size_t)b*CAPS_*OUT_;
    #pragma unroll
    for (int q=0; q<2; ++q) {
      int flat = (t + q*256)*4;
      int c = flat >> 7, o = flat & 127;
      float4 vv = *(const float4*)(vbase + flat);
      *(float4*)&sh_v[c*132 + o] = vv;
    }
    int node = t & 15, cap = t >> 4;
    sh_logit[node][cap] = logits[((size_t)b*CAPS_ + cap)*NODES_ + n0 + node];
  } else {
    int node = t & 15, cap = t >> 4;
    float cv = contrib[(size_t)b*NODES_ + n0 + node];
    sh_logit[node][cap] = cv;
    logits[((size_t)b*CAPS_ + cap)*NODES_ + n0 + node] = cv;
  }
  __syncthreads();

  if (mode >= 1) {
    int node = t >> 4, cap = t & 15;
    const float* al = &sh_alpha[(node*16+cap)*5];
    float a0=al[0],a1=al[1],a2=al[2],a3=al[3],a4=al[4];
    const float* yb = &sh_y[node*644];
    const float* vb = &sh_v[cap*132];
    float accd = 0.f;
    #pragma unroll 4
    for (int o=0; o<128; o+=4) {
      float4 y0 = *(const float4*)(yb + 0*128 + o);
      float4 y1 = *(const float4*)(yb + 1*128 + o);
      float4 y2 = *(const float4*)(yb + 2*128 + o);
      float4 y3 = *(const float4*)(yb + 3*128 + o);
      float4 y4 = *(const float4*)(yb + 4*128 + o);
      float4 vv = *(const float4*)(vb + o);
      float ux = a0*y0.x + a1*y1.x + a2*y2.x + a3*y3.x + a4*y4.x;
      float uy = a0*y0.y + a1*y1.y + a2*y2.y + a3*y3.y + a4*y4.y;
      float uz = a0*y0.z + a1*y1.z + a2*y2.z + a3*y3.z + a4*y4.z;
      float uw = a0*y0.w + a1*y1.w + a2*y2.w + a3*y3.w + a4*y4.w;
      accd += ux*vv.x + uy*vv.y + uz*vv.z + uw*vv.w;
    }
    float newl = sh_logit[node][cap] + accd;
    sh_logit[node][cap] = newl;
    logits[((size_t)b*CAPS_ + cap)*NODES_ + n0 + node] = newl;
    __syncthreads();
    if (t < 16) {
      int nd = t;
      float m = -1e30f;
      #pragma unroll
      for (int c=0;c<16;++c) m = fmaxf(m, sh_logit[nd][c]);
      float s = 0.f;
      float e[16];
      #pragma unroll
      for (int c=0;c<16;++c) { e[c] = __expf(sh_logit[nd][c]-m); s += e[c]; }
      float inv = 1.f/s;
      #pragma unroll
      for (int c=0;c<16;++c) sh_cw[nd][c] = e[c]*inv;
    }
  } else {
    int node = t >> 4, cap = t & 15;
    sh_cw[node][cap] = 1.f/16.f;
  }
  __syncthreads();

  float* spb = s_part + ((size_t)(b*32 + ch))*CAPS_*OUT_;
  #pragma unroll
  for (int sl=0; sl<2; ++sl) {
    int slot = t + sl*256;
    int c = slot >> 5;
    int o = (slot & 31) * 4;
    float4 acc = {0.f,0.f,0.f,0.f};
    #pragma unroll 4
    for (int nd=0; nd<16; ++nd) {
      const float* al = &sh_alpha[(nd*16+c)*5];
      float a0=al[0],a1=al[1],a2=al[2],a3=al[3],a4=al[4];
      const float* yb = &sh_y[nd*644 + o];
      float4 y0 = *(const float4*)(yb);
      float4 y1 = *(const float4*)(yb + 128);
      float4 y2 = *(const float4*)(yb + 256);
      float4 y3 = *(const float4*)(yb + 384);
      float4 y4 = *(const float4*)(yb + 512);
      float cw = sh_cw[nd][c];
      acc.x += cw*(a0*y0.x + a1*y1.x + a2*y2.x + a3*y3.x + a4*y4.x);
      acc.y += cw*(a0*y0.y + a1*y1.y + a2*y2.y + a3*y3.y + a4*y4.y);
      acc.z += cw*(a0*y0.z + a1*y1.z + a2*y2.z + a3*y3.z + a4*y4.z);
      acc.w += cw*(a0*y0.w + a1*y1.w + a2*y2.w + a3*y3.w + a4*y4.w);
    }
    *(float4*)(spb + c*OUT_ + o) = acc;
  }
}

// ============================================================
// squash_k<NCHK>: reduce s_part over chunks, squash, write v/out
// ============================================================
template<int NCHK>
__global__ __launch_bounds__(128) void squash_k(const float* __restrict__ s_part,
                                                float* __restrict__ out) {
  const int bc = blockIdx.x;
  const int o  = threadIdx.x;
  const int b = bc >> 4, c = bc & 15;
  const float* sp = s_part + ((size_t)(b*NCHK)*CAPS_ + c)*OUT_ + o;
  float s = 0.f;
  #pragma unroll
  for (int ch=0; ch<NCHK; ++ch) s += sp[(size_t)ch*CAPS_*OUT_];
  float ss = s*s;
  #pragma unroll
  for (int off=32; off>0; off>>=1) ss += __shfl_down(ss, off, 64);
  __shared__ float red[2];
  if ((o & 63) == 0) red[o>>6] = ss;
  __syncthreads();
  float sn = red[0] + red[1];
  float scale = (sn/(1.f+sn)) / (sqrtf(sn)+1e-8f);
  out[(size_t)bc*OUT_ + o] = scale*s;
}

// ============================================================
extern "C" void kernel_launch(void* const* d_in, const int* in_sizes, int n_in,
                              void* d_out, int out_size, void* d_ws, size_t ws_size,
                              hipStream_t stream) {
  const float* x       = (const float*)d_in[0];
  const float* contrib = (const float*)d_in[1];
  const float* W       = (const float*)d_in[2];
  const float* alpha   = (const float*)d_in[3];
  float* out = (float*)d_out;
  char*  wsb = (char*)d_ws;

  float* y      = (float*)(wsb + Y_BOFF);
  float* logits = (float*)(wsb + L_BOFF);
  float* v      = (float*)(wsb + V_BOFF);
  float* s_part = (float*)(wsb + SP_BOFF);

  if (ws_size >= (size_t)WS_NEED_BIG) {
    // BIG path: pre-split x, 64x128 gemm, 8-node route chunks.
    unsigned short* xhi  = (unsigned short*)(wsb + SP_BOFF);             // alias s_part
    unsigned short* xlo  = (unsigned short*)(wsb + SP_BOFF + XSP_SZ);
    unsigned short* bThi = (unsigned short*)(wsb + L_BOFF);              // alias logits
    unsigned short* bTlo = (unsigned short*)(wsb + L_BOFF + BT_SZ);

    conv_x<<<4096, 256, 0, stream>>>(x, xhi, xlo);
    conv_w<<<N_, 256, 0, stream>>>(W, bThi, bTlo);
    gemm_bf4<<<dim3(M_/64, N_/128), 256, 0, stream>>>(xhi, xlo, bThi, bTlo, y);

    route_step8<<<dim3(64, B_), 256, 0, stream>>>(y, alpha, contrib, logits, v, s_part, 0);
    squash_k<64><<<B_*CAPS_, 128, 0, stream>>>(s_part, v);
    for (int it=0; it<3; ++it) {
      route_step8<<<dim3(64, B_), 256, 0, stream>>>(y, alpha, contrib, logits, v, s_part, 1);
      squash_k<64><<<B_*CAPS_, 128, 0, stream>>>(s_part, (it==2) ? out : v);
    }
  } else {
    // SMALL fallback: exact round-5 structure (proven).
    unsigned short* bThi = (unsigned short*)(wsb + SP_BOFF);             // alias s_part
    unsigned short* bTlo = (unsigned short*)(wsb + SP_BOFF + BT_SZ);

    conv_w<<<N_, 256, 0, stream>>>(W, bThi, bTlo);
    gemm_insplit<<<dim3(M_/128, N_/128), 256, 0, stream>>>(x, bThi, bTlo, y);

    route_step16<<<dim3(32, B_), 256, 0, stream>>>(y, alpha, contrib, logits, v, s_part, 0);
    squash_k<32><<<B_*CAPS_, 128, 0, stream>>>(s_part, v);
    for (int it=0; it<3; ++it) {
      route_step16<<<dim3(32, B_), 256, 0, stream>>>(y, alpha, contrib, logits, v, s_part, 1);
      squash_k<32><<<B_*CAPS_, 128, 0, stream>>>(s_part, (it==2) ? out : v);
    }
  }
}

// Round 7
// 172.481 us; speedup vs baseline: 1.3502x; 1.3502x over previous
//
#include <hip/hip_runtime.h>
#include <math.h>

#define B_ 32
#define NODES_ 512
#define IN_ 256
#define OUT_ 128
#define CAPS_ 16
#define KW_ 5
#define M_ (B_*NODES_)            // 16384
#define N_ (KW_*OUT_)             // 640
#define NCH 32                    // node chunks of 16

typedef __attribute__((ext_vector_type(8))) short short8;
typedef __attribute__((ext_vector_type(4))) float f32x4;

// ---- workspace layout (bytes) ----  (round-5 proven: 51,642,368 total)
// y f32 [16384][640]             : 41,943,040
// logits f32 [B][CAPS][NODES]    :  1,048,576
// v f32 [B][CAPS][OUT]           :    262,144
// s_part f32 [B][NCH][CAPS][OUT] :  8,388,608
// bThi/bTlo bf16 [640][256]      : aliased inside s_part (dead after gemm)
#define Y_BOFF   0
#define L_BOFF   41943040
#define V_BOFF   42991616
#define SP_BOFF  43253760
#define BT_SZ    (N_*IN_*2)       // 327,680 bytes each

__device__ __forceinline__ float b2f(unsigned short u) {
  union { unsigned int i; float f; } c; c.i = ((unsigned int)u) << 16; return c.f;
}
// f32 -> bf16 round-to-nearest-even (finite inputs only)
__device__ __forceinline__ unsigned short f2b(float f) {
  union { float f; unsigned int i; } c; c.f = f;
  unsigned int u = c.i;
  u += 0x7fffu + ((u >> 16) & 1u);
  return (unsigned short)(u >> 16);
}
__device__ __forceinline__ void async_load16(const void* g, void* l) {
  __builtin_amdgcn_global_load_lds(
      (const __attribute__((address_space(1))) unsigned int*)g,
      (__attribute__((address_space(3))) unsigned int*)l, 16, 0, 0);
}

// ============================================================
// conv_w: split W into bThi/bTlo: bT*[n=k*128+o][i] = W[k][i][o]
// ============================================================
__global__ __launch_bounds__(256) void conv_w(const float* __restrict__ W,
                                              unsigned short* __restrict__ bThi,
                                              unsigned short* __restrict__ bTlo) {
  int n = blockIdx.x;           // 0..639
  int i = threadIdx.x;          // 0..255
  int k = n >> 7, o = n & 127;
  float v = W[((size_t)k*IN_ + i)*OUT_ + o];
  unsigned short h = f2b(v);
  bThi[(size_t)n*IN_ + i] = h;
  bTlo[(size_t)n*IN_ + i] = f2b(v - b2f(h));
}

// ============================================================
// gemm_dbuf: y[m][n] = sum_i x[m][i]*bT[n][i]  (f32 in/out, split-bf16
// MFMA hi*hi + hi*lo + lo*hi, f32 accumulate).
// 128x128 tile, BK=32, 4 waves 2x2, 4x4 frags of mfma 16x16x32.
// 2-PHASE DOUBLE BUFFER: stage tile k+1 BEFORE computing tile k; one
// (implicit vmcnt(0)) barrier per tile -> load latency hides under MFMA.
// A staged f32 [cg][row][4]; B hi/lo bf16 [cg][row][8]; in-fragment
// A split (VALU overlaps MFMA across waves). Swapped-operand mfma ->
// n-quad in regs -> float4 y stores.
// ============================================================
__global__ __launch_bounds__(256) void gemm_dbuf(const float* __restrict__ x,
                                                 const unsigned short* __restrict__ bThi,
                                                 const unsigned short* __restrict__ bTlo,
                                                 float* __restrict__ y) {
  __shared__ float A_lds[2][8*128*4];    // 2 x 16 KB
  __shared__ short Bh_lds[2][4*128*8];   // 2 x 8 KB
  __shared__ short Bl_lds[2][4*128*8];   // 2 x 8 KB   -> 64 KB total
  const int t    = threadIdx.x;
  const int w    = t >> 6;
  const int lane = t & 63;
  const int wm   = w >> 1;
  const int wn   = w & 1;
  const int m0   = blockIdx.x * 128;
  const int n0   = blockIdx.y * 128;
  const int lrow = lane & 15;
  const int lk   = lane >> 4;

  f32x4 acc[4][4];
  #pragma unroll
  for (int i=0;i<4;++i)
    #pragma unroll
    for (int j=0;j<4;++j) acc[i][j] = (f32x4){0.f,0.f,0.f,0.f};

#define STAGE_TILE(buf, kb) do {                                              \
    _Pragma("unroll")                                                         \
    for (int q=0; q<4; ++q) {                                                 \
      int d0 = q*256 + w*64; int d = d0 + lane;                               \
      int cg = d >> 7;  int r = d & 127;                                      \
      async_load16(x + (size_t)(m0 + r)*IN_ + (kb) + cg*4, &A_lds[buf][d0*4]);\
    }                                                                         \
    _Pragma("unroll")                                                         \
    for (int q=0; q<2; ++q) {                                                 \
      int d0 = q*256 + w*64; int d = d0 + lane;                               \
      int cg = d >> 7;  int r = d & 127;                                      \
      async_load16(bThi + (size_t)(n0 + r)*IN_ + (kb) + cg*8, &Bh_lds[buf][d0*8]); \
      async_load16(bTlo + (size_t)(n0 + r)*IN_ + (kb) + cg*8, &Bl_lds[buf][d0*8]); \
    }                                                                         \
  } while(0)

  STAGE_TILE(0, 0);
  __syncthreads();              // drain vmcnt(0): buf0 ready
  int cur = 0;

  #pragma unroll
  for (int kbi = 0; kbi < 8; ++kbi) {
    if (kbi < 7) STAGE_TILE(cur^1, (kbi+1)*32);   // prefetch next tile

    const float* Ac  = A_lds[cur];
    const short* Bhc = Bh_lds[cur];
    const short* Blc = Bl_lds[cur];

    short8 ah[4], al[4], bh[4], bl[4];
    #pragma unroll
    for (int mi=0; mi<4; ++mi) {
      int row_a = wm*64 + mi*16 + lrow;
      f32x4 a0 = *(const f32x4*)&Ac[((2*lk  )*128 + row_a)*4];
      f32x4 a1 = *(const f32x4*)&Ac[((2*lk+1)*128 + row_a)*4];
      #pragma unroll
      for (int j=0; j<8; ++j) {
        float f = (j < 4) ? a0[j] : a1[j-4];
        unsigned short h = f2b(f);
        ah[mi][j] = (short)h;
        al[mi][j] = (short)f2b(f - b2f(h));
      }
    }
    #pragma unroll
    for (int ni=0; ni<4; ++ni) {
      int row_b = wn*64 + ni*16 + lrow;
      bh[ni] = *(const short8*)&Bhc[(lk*128 + row_b)*8];
      bl[ni] = *(const short8*)&Blc[(lk*128 + row_b)*8];
    }
    #pragma unroll
    for (int mi=0; mi<4; ++mi)
      #pragma unroll
      for (int ni=0; ni<4; ++ni) {
        acc[mi][ni] = __builtin_amdgcn_mfma_f32_16x16x32_bf16(bh[ni], ah[mi], acc[mi][ni], 0, 0, 0);
        acc[mi][ni] = __builtin_amdgcn_mfma_f32_16x16x32_bf16(bh[ni], al[mi], acc[mi][ni], 0, 0, 0);
        acc[mi][ni] = __builtin_amdgcn_mfma_f32_16x16x32_bf16(bl[ni], ah[mi], acc[mi][ni], 0, 0, 0);
      }
    __syncthreads();            // drains vmcnt(0): next buf staged; all waves done with cur
    cur ^= 1;
  }
#undef STAGE_TILE

  // epilogue: lane holds C[m = lane&15][n-quad = (lane>>4)*4 + reg]
  #pragma unroll
  for (int mi=0; mi<4; ++mi) {
    int m = m0 + wm*64 + mi*16 + lrow;
    #pragma unroll
    for (int ni=0; ni<4; ++ni) {
      int nb = n0 + wn*64 + ni*16 + lk*4;
      float4 o = {acc[mi][ni][0], acc[mi][ni][1], acc[mi][ni][2], acc[mi][ni][3]};
      *(float4*)(y + (size_t)m*N_ + nb) = o;
    }
  }
}

// ============================================================
// route_step: one routing sweep for 16 nodes of one batch b (f32 y).
// v read directly from global (L2-resident) -> LDS 55->48 KB -> 3 blk/CU.
// mode 0: init logits from contribution, c = 1/16 uniform.
// mode 1: a = u.v ; logits += a ; c = softmax(logits).
// ============================================================
__global__ __launch_bounds__(256) void route_step(const float* __restrict__ y,
                                                  const float* __restrict__ alpha,
                                                  const float* __restrict__ contrib,
                                                  float* __restrict__ logits,
                                                  const float* __restrict__ vin,
                                                  float* __restrict__ s_part,
                                                  int mode) {
  __shared__ __align__(16) float sh_y[16*644];      // 41.2 KB [node][k*128+o]
  __shared__ __align__(16) float sh_alpha[16*16*5]; //  5.1 KB [node][cap][k]
  __shared__ float sh_logit[16][16];
  __shared__ float sh_cw[16][16];

  const int t  = threadIdx.x;
  const int ch = blockIdx.x;   // 0..31
  const int b  = blockIdx.y;   // 0..31
  const int n0 = ch*16;

  // ---- stage y: 16 nodes x 640 contiguous floats ----
  const float* ybase = y + ((size_t)(b*NODES_ + n0))*KW_*OUT_;
  #pragma unroll
  for (int q=0; q<10; ++q) {
    int idx4 = t + q*256;           // 0..2559
    int flat = idx4*4;
    int node = flat / 640;
    int rem  = flat - node*640;
    float4 vv = *(const float4*)(ybase + flat);
    *(float4*)&sh_y[node*644 + rem] = vv;
  }
  // ---- stage alpha: 320 float4 strided over 256 threads ----
  const float* abase = alpha + (size_t)n0*CAPS_*KW_;
  for (int i = t; i < 320; i += 256) {
    float4 av = *(const float4*)(abase + i*4);
    *(float4*)&sh_alpha[i*4] = av;
  }
  {
    int node = t & 15, cap = t >> 4;
    if (mode >= 1) {
      sh_logit[node][cap] = logits[((size_t)b*CAPS_ + cap)*NODES_ + n0 + node];
    } else {
      float cv = contrib[(size_t)b*NODES_ + n0 + node];
      sh_logit[node][cap] = cv;
      logits[((size_t)b*CAPS_ + cap)*NODES_ + n0 + node] = cv;
    }
  }
  __syncthreads();

  if (mode >= 1) {
    // ---- phase 1: a[node][cap] = sum_o u*v (v streamed from global) ----
    int node = t >> 4, cap = t & 15;
    const float* al = &sh_alpha[(node*16+cap)*5];
    float a0=al[0],a1=al[1],a2=al[2],a3=al[3],a4=al[4];
    const float* yb = &sh_y[node*644];
    const float* vb = vin + (size_t)b*CAPS_*OUT_ + (size_t)cap*OUT_;
    float accd = 0.f;
    #pragma unroll 4
    for (int o=0; o<128; o+=4) {
      float4 y0 = *(const float4*)(yb + 0*128 + o);
      float4 y1 = *(const float4*)(yb + 1*128 + o);
      float4 y2 = *(const float4*)(yb + 2*128 + o);
      float4 y3 = *(const float4*)(yb + 3*128 + o);
      float4 y4 = *(const float4*)(yb + 4*128 + o);
      float4 vv = *(const float4*)(vb + o);
      float ux = a0*y0.x + a1*y1.x + a2*y2.x + a3*y3.x + a4*y4.x;
      float uy = a0*y0.y + a1*y1.y + a2*y2.y + a3*y3.y + a4*y4.y;
      float uz = a0*y0.z + a1*y1.z + a2*y2.z + a3*y3.z + a4*y4.z;
      float uw = a0*y0.w + a1*y1.w + a2*y2.w + a3*y3.w + a4*y4.w;
      accd += ux*vv.x + uy*vv.y + uz*vv.z + uw*vv.w;
    }
    float newl = sh_logit[node][cap] + accd;
    sh_logit[node][cap] = newl;
    logits[((size_t)b*CAPS_ + cap)*NODES_ + n0 + node] = newl;
    __syncthreads();
    // softmax over caps, one thread per node
    if (t < 16) {
      int nd = t;
      float m = -1e30f;
      #pragma unroll
      for (int c=0;c<16;++c) m = fmaxf(m, sh_logit[nd][c]);
      float s = 0.f;
      float e[16];
      #pragma unroll
      for (int c=0;c<16;++c) { e[c] = __expf(sh_logit[nd][c]-m); s += e[c]; }
      float inv = 1.f/s;
      #pragma unroll
      for (int c=0;c<16;++c) sh_cw[nd][c] = e[c]*inv;
    }
  } else {
    int node = t >> 4, cap = t & 15;
    sh_cw[node][cap] = 1.f/16.f;
  }
  __syncthreads();

  // ---- phase 2: s_part[c][o] = sum_node cw * u ----
  float* spb = s_part + ((size_t)(b*NCH + ch))*CAPS_*OUT_;
  #pragma unroll
  for (int sl=0; sl<2; ++sl) {
    int slot = t + sl*256;
    int c = slot >> 5;          // 0..15
    int o = (slot & 31) * 4;    // 0..124
    float4 acc = {0.f,0.f,0.f,0.f};
    #pragma unroll 4
    for (int nd=0; nd<16; ++nd) {
      const float* al = &sh_alpha[(nd*16+c)*5];
      float a0=al[0],a1=al[1],a2=al[2],a3=al[3],a4=al[4];
      const float* yb = &sh_y[nd*644 + o];
      float4 y0 = *(const float4*)(yb);
      float4 y1 = *(const float4*)(yb + 128);
      float4 y2 = *(const float4*)(yb + 256);
      float4 y3 = *(const float4*)(yb + 384);
      float4 y4 = *(const float4*)(yb + 512);
      float cw = sh_cw[nd][c];
      acc.x += cw*(a0*y0.x + a1*y1.x + a2*y2.x + a3*y3.x + a4*y4.x);
      acc.y += cw*(a0*y0.y + a1*y1.y + a2*y2.y + a3*y3.y + a4*y4.y);
      acc.z += cw*(a0*y0.z + a1*y1.z + a2*y2.z + a3*y3.z + a4*y4.z);
      acc.w += cw*(a0*y0.w + a1*y1.w + a2*y2.w + a3*y3.w + a4*y4.w);
    }
    *(float4*)(spb + c*OUT_ + o) = acc;
  }
}

// ============================================================
// squash_k: reduce s_part over chunks, squash, write v (or out)
// ============================================================
__global__ __launch_bounds__(128) void squash_k(const float* __restrict__ s_part,
                                                float* __restrict__ out) {
  const int bc = blockIdx.x;       // b*16+c
  const int o  = threadIdx.x;      // 0..127
  const int b = bc >> 4, c = bc & 15;
  const float* sp = s_part + ((size_t)(b*NCH)*CAPS_ + c)*OUT_ + o;
  float s = 0.f;
  #pragma unroll
  for (int ch=0; ch<NCH; ++ch) s += sp[(size_t)ch*CAPS_*OUT_];
  float ss = s*s;
  #pragma unroll
  for (int off=32; off>0; off>>=1) ss += __shfl_down(ss, off, 64);
  __shared__ float red[2];
  if ((o & 63) == 0) red[o>>6] = ss;
  __syncthreads();
  float sn = red[0] + red[1];
  float scale = (sn/(1.f+sn)) / (sqrtf(sn)+1e-8f);
  out[(size_t)bc*OUT_ + o] = scale*s;
}

// ============================================================
extern "C" void kernel_launch(void* const* d_in, const int* in_sizes, int n_in,
                              void* d_out, int out_size, void* d_ws, size_t ws_size,
                              hipStream_t stream) {
  const float* x       = (const float*)d_in[0];
  const float* contrib = (const float*)d_in[1];
  const float* W       = (const float*)d_in[2];
  const float* alpha   = (const float*)d_in[3];
  float* out = (float*)d_out;
  char*  wsb = (char*)d_ws;

  float* y             = (float*)(wsb + Y_BOFF);
  float* logits        = (float*)(wsb + L_BOFF);
  float* v             = (float*)(wsb + V_BOFF);
  float* s_part        = (float*)(wsb + SP_BOFF);
  // bT hi/lo alias the s_part region (consumed before s_part first written)
  unsigned short* bThi = (unsigned short*)(wsb + SP_BOFF);
  unsigned short* bTlo = (unsigned short*)(wsb + SP_BOFF + BT_SZ);

  conv_w<<<N_, 256, 0, stream>>>(W, bThi, bTlo);
  gemm_dbuf<<<dim3(M_/128, N_/128), 256, 0, stream>>>(x, bThi, bTlo, y);

  route_step<<<dim3(NCH, B_), 256, 0, stream>>>(y, alpha, contrib, logits, v, s_part, 0);
  squash_k<<<B_*CAPS_, 128, 0, stream>>>(s_part, v);

  for (int it=0; it<3; ++it) {
    route_step<<<dim3(NCH, B_), 256, 0, stream>>>(y, alpha, contrib, logits, v, s_part, 1);
    squash_k<<<B_*CAPS_, 128, 0, stream>>>(s_part, (it==2) ? out : v);
  }
}

// Round 8
// 164.113 us; speedup vs baseline: 1.4190x; 1.0510x over previous
//
#include <hip/hip_runtime.h>
#include <math.h>

#define B_ 32
#define NODES_ 512
#define IN_ 256
#define OUT_ 128
#define CAPS_ 16
#define KW_ 5
#define M_ (B_*NODES_)            // 16384
#define N_ (KW_*OUT_)             // 640
#define NCH 32                    // node chunks of 16

typedef __attribute__((ext_vector_type(8))) short short8;
typedef __attribute__((ext_vector_type(4))) float f32x4;

// ---- workspace layout (bytes) ---- (round-5 proven: 51,642,368 total)
// y f32 [16384][640] ; logits ; v ; s_part ; bT hi/lo aliased in s_part
#define Y_BOFF   0
#define L_BOFF   41943040
#define V_BOFF   42991616
#define SP_BOFF  43253760
#define BT_SZ    (N_*IN_*2)       // 327,680 bytes each

__device__ __forceinline__ float b2f(unsigned short u) {
  union { unsigned int i; float f; } c; c.i = ((unsigned int)u) << 16; return c.f;
}
// f32 -> bf16 round-to-nearest-even (finite inputs only)
__device__ __forceinline__ unsigned short f2b(float f) {
  union { float f; unsigned int i; } c; c.f = f;
  unsigned int u = c.i;
  u += 0x7fffu + ((u >> 16) & 1u);
  return (unsigned short)(u >> 16);
}
__device__ __forceinline__ void async_load16(const void* g, void* l) {
  __builtin_amdgcn_global_load_lds(
      (const __attribute__((address_space(1))) unsigned int*)g,
      (__attribute__((address_space(3))) unsigned int*)l, 16, 0, 0);
}

// ============================================================
// conv_w: split W into bThi/bTlo: bT*[n=k*128+o][i] = W[k][i][o]
// ============================================================
__global__ __launch_bounds__(256) void conv_w(const float* __restrict__ W,
                                              unsigned short* __restrict__ bThi,
                                              unsigned short* __restrict__ bTlo) {
  int n = blockIdx.x;           // 0..639
  int i = threadIdx.x;          // 0..255
  int k = n >> 7, o = n & 127;
  float v = W[((size_t)k*IN_ + i)*OUT_ + o];
  unsigned short h = f2b(v);
  bThi[(size_t)n*IN_ + i] = h;
  bTlo[(size_t)n*IN_ + i] = f2b(v - b2f(h));
}

// ============================================================
// gemm64: y[m][n] = sum_i x[m][i]*bT[n][i]  (split-bf16 MFMA
// hi*hi + hi*lo + lo*hi, f32 accumulate). 64x64 tile, BK=32,
// 4 waves 2x2 (wave tile 32x32), 2x2 frags of mfma 16x16x32.
// 2560 blocks, 16 KB LDS -> high blocks/CU: TLP hides the per-tile
// stage->drain->compute latency (dbuf at source level was null).
// ============================================================
__global__ __launch_bounds__(256) void gemm64(const float* __restrict__ x,
                                              const unsigned short* __restrict__ bThi,
                                              const unsigned short* __restrict__ bTlo,
                                              float* __restrict__ y) {
  __shared__ float A_lds[8*64*4];     // 8 KB  [cg][row][4f]
  __shared__ short Bh_lds[4*64*8];    // 4 KB  [cg][row][8e]
  __shared__ short Bl_lds[4*64*8];    // 4 KB
  const int t    = threadIdx.x;
  const int w    = t >> 6;
  const int lane = t & 63;
  const int wm   = w >> 1;          // 0..1
  const int wn   = w & 1;           // 0..1
  const int m0   = blockIdx.x * 64;
  const int n0   = blockIdx.y * 64;
  const int lrow = lane & 15;
  const int lk   = lane >> 4;       // 0..3

  f32x4 acc[2][2];
  #pragma unroll
  for (int i=0;i<2;++i)
    #pragma unroll
    for (int j=0;j<2;++j) acc[i][j] = (f32x4){0.f,0.f,0.f,0.f};

  for (int kb = 0; kb < IN_; kb += 32) {
    // stage A: 512 chunks (64 rows x 8 chunks of 4 f32)
    #pragma unroll
    for (int q=0; q<2; ++q) {
      int d0 = q*256 + w*64; int d = d0 + lane;
      int cg = d >> 6;  int r = d & 63;
      async_load16(x + (size_t)(m0 + r)*IN_ + kb + cg*4, &A_lds[d0*4]);
    }
    // stage B hi/lo: 256 chunks each (64 rows x 4 chunks of 8 bf16)
    {
      int d0 = w*64; int d = t;
      int cg = d >> 6;  int r = d & 63;
      async_load16(bThi + (size_t)(n0 + r)*IN_ + kb + cg*8, &Bh_lds[d0*8]);
      async_load16(bTlo + (size_t)(n0 + r)*IN_ + kb + cg*8, &Bl_lds[d0*8]);
    }
    __syncthreads();

    short8 ah[2], al[2], bh[2], bl[2];
    #pragma unroll
    for (int mi=0; mi<2; ++mi) {
      int row_a = wm*32 + mi*16 + lrow;
      f32x4 a0 = *(const f32x4*)&A_lds[((2*lk  )*64 + row_a)*4];
      f32x4 a1 = *(const f32x4*)&A_lds[((2*lk+1)*64 + row_a)*4];
      #pragma unroll
      for (int j=0; j<8; ++j) {
        float f = (j < 4) ? a0[j] : a1[j-4];
        unsigned short h = f2b(f);
        ah[mi][j] = (short)h;
        al[mi][j] = (short)f2b(f - b2f(h));
      }
    }
    #pragma unroll
    for (int ni=0; ni<2; ++ni) {
      int row_b = wn*32 + ni*16 + lrow;
      bh[ni] = *(const short8*)&Bh_lds[(lk*64 + row_b)*8];
      bl[ni] = *(const short8*)&Bl_lds[(lk*64 + row_b)*8];
    }
    #pragma unroll
    for (int mi=0; mi<2; ++mi)
      #pragma unroll
      for (int ni=0; ni<2; ++ni) {
        acc[mi][ni] = __builtin_amdgcn_mfma_f32_16x16x32_bf16(bh[ni], ah[mi], acc[mi][ni], 0, 0, 0);
        acc[mi][ni] = __builtin_amdgcn_mfma_f32_16x16x32_bf16(bh[ni], al[mi], acc[mi][ni], 0, 0, 0);
        acc[mi][ni] = __builtin_amdgcn_mfma_f32_16x16x32_bf16(bl[ni], ah[mi], acc[mi][ni], 0, 0, 0);
      }
    __syncthreads();
  }

  // epilogue: lane holds C[m = lane&15][n-quad = (lane>>4)*4 + reg]
  #pragma unroll
  for (int mi=0; mi<2; ++mi) {
    int m = m0 + wm*32 + mi*16 + lrow;
    #pragma unroll
    for (int ni=0; ni<2; ++ni) {
      int nb = n0 + wn*32 + ni*16 + lk*4;
      float4 o = {acc[mi][ni][0], acc[mi][ni][1], acc[mi][ni][2], acc[mi][ni][3]};
      *(float4*)(y + (size_t)m*N_ + nb) = o;
    }
  }
}

// ============================================================
// route_step: one routing sweep for 16 nodes of one batch b (f32 y).
// sh_y unpadded (640) -> staged via global_load_lds; all y reads in
// phase 1 AND phase 2 are same-address broadcasts across 16 lanes
// (phase 2 mapping: c = slot&15 fast, o-quad = slot>>4).
// ============================================================
__global__ __launch_bounds__(256) void route_step(const float* __restrict__ y,
                                                  const float* __restrict__ alpha,
                                                  const float* __restrict__ contrib,
                                                  float* __restrict__ logits,
                                                  const float* __restrict__ vin,
                                                  float* __restrict__ s_part,
                                                  int mode) {
  __shared__ __align__(16) float sh_y[16*640];      // 40 KB [node][k*128+o]
  __shared__ __align__(16) float sh_v[16*132];      //  8.4 KB [cap][o] pad 132
  __shared__ __align__(16) float sh_alpha[16*16*5]; //  5.1 KB [node][cap][k]
  __shared__ float sh_logit[16][16];
  __shared__ float sh_cw[16][16];

  const int t  = threadIdx.x;
  const int ch = blockIdx.x;   // 0..31
  const int b  = blockIdx.y;   // 0..31
  const int n0 = ch*16;

  // ---- stage y: 16 nodes x 640 f32 = 40 KB contiguous, async 10/thread ----
  const float* ybase = y + ((size_t)(b*NODES_ + n0))*KW_*OUT_;
  #pragma unroll
  for (int q=0; q<10; ++q) {
    int d0 = q*256 + (t & ~63);           // wave-uniform chunk base
    async_load16(ybase + (size_t)(d0 + (t & 63))*4, &sh_y[d0*4]);
  }
  // ---- stage alpha: 320 float4 strided over 256 threads ----
  const float* abase = alpha + (size_t)n0*CAPS_*KW_;
  for (int i = t; i < 320; i += 256) {
    float4 av = *(const float4*)(abase + i*4);
    *(float4*)&sh_alpha[i*4] = av;
  }
  if (mode >= 1) {
    // stage v[b]: 16 caps x 128 (padded 132 rows for phase-1 bank spread)
    const float* vbase = vin + (size_t)b*CAPS_*OUT_;
    #pragma unroll
    for (int q=0; q<2; ++q) {
      int flat = (t + q*256)*4;
      int c = flat >> 7, o = flat & 127;
      float4 vv = *(const float4*)(vbase + flat);
      *(float4*)&sh_v[c*132 + o] = vv;
    }
    int node = t & 15, cap = t >> 4;
    sh_logit[node][cap] = logits[((size_t)b*CAPS_ + cap)*NODES_ + n0 + node];
  } else {
    int node = t & 15, cap = t >> 4;
    float cv = contrib[(size_t)b*NODES_ + n0 + node];
    sh_logit[node][cap] = cv;
    logits[((size_t)b*CAPS_ + cap)*NODES_ + n0 + node] = cv;
  }
  __syncthreads();

  if (mode >= 1) {
    // ---- phase 1: a[node][cap] = sum_o u*v  (y reads broadcast over caps) ----
    int node = t >> 4, cap = t & 15;
    const float* al = &sh_alpha[(node*16+cap)*5];
    float a0=al[0],a1=al[1],a2=al[2],a3=al[3],a4=al[4];
    const float* yb = &sh_y[node*640];
    const float* vb = &sh_v[cap*132];
    float accd = 0.f;
    #pragma unroll 4
    for (int o=0; o<128; o+=4) {
      float4 y0 = *(const float4*)(yb + 0*128 + o);
      float4 y1 = *(const float4*)(yb + 1*128 + o);
      float4 y2 = *(const float4*)(yb + 2*128 + o);
      float4 y3 = *(const float4*)(yb + 3*128 + o);
      float4 y4 = *(const float4*)(yb + 4*128 + o);
      float4 vv = *(const float4*)(vb + o);
      float ux = a0*y0.x + a1*y1.x + a2*y2.x + a3*y3.x + a4*y4.x;
      float uy = a0*y0.y + a1*y1.y + a2*y2.y + a3*y3.y + a4*y4.y;
      float uz = a0*y0.z + a1*y1.z + a2*y2.z + a3*y3.z + a4*y4.z;
      float uw = a0*y0.w + a1*y1.w + a2*y2.w + a3*y3.w + a4*y4.w;
      accd += ux*vv.x + uy*vv.y + uz*vv.z + uw*vv.w;
    }
    float newl = sh_logit[node][cap] + accd;
    sh_logit[node][cap] = newl;
    logits[((size_t)b*CAPS_ + cap)*NODES_ + n0 + node] = newl;
    __syncthreads();
    // softmax over caps, one thread per node
    if (t < 16) {
      int nd = t;
      float m = -1e30f;
      #pragma unroll
      for (int c=0;c<16;++c) m = fmaxf(m, sh_logit[nd][c]);
      float s = 0.f;
      float e[16];
      #pragma unroll
      for (int c=0;c<16;++c) { e[c] = __expf(sh_logit[nd][c]-m); s += e[c]; }
      float inv = 1.f/s;
      #pragma unroll
      for (int c=0;c<16;++c) sh_cw[nd][c] = e[c]*inv;
    }
  } else {
    int node = t >> 4, cap = t & 15;
    sh_cw[node][cap] = 1.f/16.f;
  }
  __syncthreads();

  // ---- phase 2: s_part[c][o] = sum_node cw*u ----
  // c = slot&15 (fast across lanes) -> 16 lanes share one y address
  // per read = LDS broadcast; effective y traffic /16.
  float* spb = s_part + ((size_t)(b*NCH + ch))*CAPS_*OUT_;
  #pragma unroll
  for (int sl=0; sl<2; ++sl) {
    int slot = t + sl*256;
    int c  = slot & 15;
    int o  = (slot >> 4) * 4;   // 0..124
    float4 acc = {0.f,0.f,0.f,0.f};
    #pragma unroll 4
    for (int nd=0; nd<16; ++nd) {
      const float* al = &sh_alpha[(nd*16+c)*5];
      float a0=al[0],a1=al[1],a2=al[2],a3=al[3],a4=al[4];
      const float* yb = &sh_y[nd*640 + o];
      float4 y0 = *(const float4*)(yb);
      float4 y1 = *(const float4*)(yb + 128);
      float4 y2 = *(const float4*)(yb + 256);
      float4 y3 = *(const float4*)(yb + 384);
      float4 y4 = *(const float4*)(yb + 512);
      float cw = sh_cw[nd][c];
      acc.x += cw*(a0*y0.x + a1*y1.x + a2*y2.x + a3*y3.x + a4*y4.x);
      acc.y += cw*(a0*y0.y + a1*y1.y + a2*y2.y + a3*y3.y + a4*y4.y);
      acc.z += cw*(a0*y0.z + a1*y1.z + a2*y2.z + a3*y3.z + a4*y4.z);
      acc.w += cw*(a0*y0.w + a1*y1.w + a2*y2.w + a3*y3.w + a4*y4.w);
    }
    *(float4*)(spb + c*OUT_ + o) = acc;
  }
}

// ============================================================
// squash_k: reduce s_part over chunks, squash, write v (or out)
// ============================================================
__global__ __launch_bounds__(128) void squash_k(const float* __restrict__ s_part,
                                                float* __restrict__ out) {
  const int bc = blockIdx.x;       // b*16+c
  const int o  = threadIdx.x;      // 0..127
  const int b = bc >> 4, c = bc & 15;
  const float* sp = s_part + ((size_t)(b*NCH)*CAPS_ + c)*OUT_ + o;
  float s = 0.f;
  #pragma unroll
  for (int ch=0; ch<NCH; ++ch) s += sp[(size_t)ch*CAPS_*OUT_];
  float ss = s*s;
  #pragma unroll
  for (int off=32; off>0; off>>=1) ss += __shfl_down(ss, off, 64);
  __shared__ float red[2];
  if ((o & 63) == 0) red[o>>6] = ss;
  __syncthreads();
  float sn = red[0] + red[1];
  float scale = (sn/(1.f+sn)) / (sqrtf(sn)+1e-8f);
  out[(size_t)bc*OUT_ + o] = scale*s;
}

// ============================================================
extern "C" void kernel_launch(void* const* d_in, const int* in_sizes, int n_in,
                              void* d_out, int out_size, void* d_ws, size_t ws_size,
                              hipStream_t stream) {
  const float* x       = (const float*)d_in[0];
  const float* contrib = (const float*)d_in[1];
  const float* W       = (const float*)d_in[2];
  const float* alpha   = (const float*)d_in[3];
  float* out = (float*)d_out;
  char*  wsb = (char*)d_ws;

  float* y             = (float*)(wsb + Y_BOFF);
  float* logits        = (float*)(wsb + L_BOFF);
  float* v             = (float*)(wsb + V_BOFF);
  float* s_part        = (float*)(wsb + SP_BOFF);
  // bT hi/lo alias the s_part region (consumed before s_part first written)
  unsigned short* bThi = (unsigned short*)(wsb + SP_BOFF);
  unsigned short* bTlo = (unsigned short*)(wsb + SP_BOFF + BT_SZ);

  conv_w<<<N_, 256, 0, stream>>>(W, bThi, bTlo);
  gemm64<<<dim3(M_/64, N_/64), 256, 0, stream>>>(x, bThi, bTlo, y);

  route_step<<<dim3(NCH, B_), 256, 0, stream>>>(y, alpha, contrib, logits, v, s_part, 0);
  squash_k<<<B_*CAPS_, 128, 0, stream>>>(s_part, v);

  for (int it=0; it<3; ++it) {
    route_step<<<dim3(NCH, B_), 256, 0, stream>>>(y, alpha, contrib, logits, v, s_part, 1);
    squash_k<<<B_*CAPS_, 128, 0, stream>>>(s_part, (it==2) ? out : v);
  }
}

// Round 9
// 150.409 us; speedup vs baseline: 1.5483x; 1.0911x over previous
//
#include <hip/hip_runtime.h>
#include <math.h>

#define B_ 32
#define NODES_ 512
#define IN_ 256
#define OUT_ 128
#define CAPS_ 16
#define KW_ 5
#define M_ (B_*NODES_)            // 16384
#define N_ (KW_*OUT_)             // 640
#define NCH 32                    // node chunks of 16

typedef __attribute__((ext_vector_type(8))) short short8;
typedef __attribute__((ext_vector_type(4))) float f32x4;

// ---- workspace layout (bytes) ---- (round-5 proven: 51,642,368 total)
// y f32 [16384][640] ; logits ; v ; s_part ; bT hi/lo aliased in s_part
#define Y_BOFF   0
#define L_BOFF   41943040
#define V_BOFF   42991616
#define SP_BOFF  43253760
#define BT_SZ    (N_*IN_*2)       // 327,680 bytes each

__device__ __forceinline__ float b2f(unsigned short u) {
  union { unsigned int i; float f; } c; c.i = ((unsigned int)u) << 16; return c.f;
}
// f32 -> bf16 round-to-nearest-even (finite inputs only)
__device__ __forceinline__ unsigned short f2b(float f) {
  union { float f; unsigned int i; } c; c.f = f;
  unsigned int u = c.i;
  u += 0x7fffu + ((u >> 16) & 1u);
  return (unsigned short)(u >> 16);
}
__device__ __forceinline__ void async_load16(const void* g, void* l) {
  __builtin_amdgcn_global_load_lds(
      (const __attribute__((address_space(1))) unsigned int*)g,
      (__attribute__((address_space(3))) unsigned int*)l, 16, 0, 0);
}

// ============================================================
// conv_w: split W into K-MAJOR bf16 hi/lo panels:
//   bT*[kg][n][j] = W[k][i=kg*8+j][o],  n = k*128+o, kg = i/8.
// K-major makes the gemm's per-step B stage a flat contiguous
// 40 KB copy (perfect global_load_lds coalescing, linear dest).
// ============================================================
__global__ __launch_bounds__(256) void conv_w(const float* __restrict__ W,
                                              unsigned short* __restrict__ bThi,
                                              unsigned short* __restrict__ bTlo) {
  int n = blockIdx.x;           // 0..639
  int i = threadIdx.x;          // 0..255
  int k = n >> 7, o = n & 127;
  float v = W[((size_t)k*IN_ + i)*OUT_ + o];
  unsigned short h = f2b(v);
  size_t dst = ((size_t)(i >> 3)*N_ + n)*8 + (i & 7);
  bThi[dst] = h;
  bTlo[dst] = f2b(v - b2f(h));
}

// ============================================================
// gemm_fn: y[m][n] = sum_i x[m][i]*bT[n][i]  (split-bf16 MFMA
// hi*hi + hi*lo + lo*hi, f32 accumulate).
// FULL-N blocks: 256 blocks x 64 rows, each covers all 640 cols
// -> x read exactly ONCE (no A re-reads; prior tiled versions'
// 84-168 MB of L3 A-traffic was the measured bottleneck).
// 512 thr = 8 waves, one 80-col strip each; 4 m-frags x 5 n-frags.
// LDS 88 KB: A[8cg][64][4f] + B hi/lo [4kg][640][8] (flat-staged).
// ============================================================
__global__ __launch_bounds__(512) void gemm_fn(const float* __restrict__ x,
                                               const unsigned short* __restrict__ bThi,
                                               const unsigned short* __restrict__ bTlo,
                                               float* __restrict__ y) {
  __shared__ float A_lds[8*64*4];      //  8 KB
  __shared__ short Bh_lds[4*640*8];    // 40 KB
  __shared__ short Bl_lds[4*640*8];    // 40 KB
  const int t    = threadIdx.x;
  const int w    = t >> 6;             // wave 0..7 -> N-strip w*80
  const int lane = t & 63;
  const int lrow = lane & 15;
  const int lk   = lane >> 4;          // 0..3
  const int m0   = blockIdx.x * 64;
  const int wn0  = w * 80;

  f32x4 acc[4][5];
  #pragma unroll
  for (int i=0;i<4;++i)
    #pragma unroll
    for (int j=0;j<5;++j) acc[i][j] = (f32x4){0.f,0.f,0.f,0.f};

  for (int kbi = 0; kbi < 8; ++kbi) {
    const int kb = kbi*32;
    // ---- stage A: 512 chunks, cg = w (uniform), row = lane ----
    async_load16(x + (size_t)(m0 + lane)*IN_ + kb + w*4, &A_lds[(w*64)*4]);
    // ---- stage B hi/lo: flat contiguous 40 KB each (2560 chunks) ----
    const unsigned short* bh_src = bThi + (size_t)kbi*4*N_*8;
    const unsigned short* bl_src = bTlo + (size_t)kbi*4*N_*8;
    #pragma unroll
    for (int q=0; q<5; ++q) {
      int db = q*512 + w*64;           // wave-uniform chunk base
      async_load16(bh_src + (size_t)(db + lane)*8, &Bh_lds[db*8]);
      async_load16(bl_src + (size_t)(db + lane)*8, &Bl_lds[db*8]);
    }
    __syncthreads();

    // ---- A fragments: read f32, split hi/lo in-register ----
    short8 ah[4], al[4];
    #pragma unroll
    for (int mi=0; mi<4; ++mi) {
      int row = mi*16 + lrow;
      f32x4 a0 = *(const f32x4*)&A_lds[((2*lk  )*64 + row)*4];
      f32x4 a1 = *(const f32x4*)&A_lds[((2*lk+1)*64 + row)*4];
      #pragma unroll
      for (int j=0; j<8; ++j) {
        float f = (j < 4) ? a0[j] : a1[j-4];
        unsigned short h = f2b(f);
        ah[mi][j] = (short)h;
        al[mi][j] = (short)f2b(f - b2f(h));
      }
    }
    // ---- MFMA: 5 n-frags x 4 m-frags x 3 passes ----
    #pragma unroll
    for (int ni=0; ni<5; ++ni) {
      int nb = wn0 + ni*16 + lrow;
      short8 bh = *(const short8*)&Bh_lds[(lk*N_ + nb)*8];
      short8 bl = *(const short8*)&Bl_lds[(lk*N_ + nb)*8];
      #pragma unroll
      for (int mi=0; mi<4; ++mi) {
        acc[mi][ni] = __builtin_amdgcn_mfma_f32_16x16x32_bf16(bh, ah[mi], acc[mi][ni], 0, 0, 0);
        acc[mi][ni] = __builtin_amdgcn_mfma_f32_16x16x32_bf16(bh, al[mi], acc[mi][ni], 0, 0, 0);
        acc[mi][ni] = __builtin_amdgcn_mfma_f32_16x16x32_bf16(bl, ah[mi], acc[mi][ni], 0, 0, 0);
      }
    }
    __syncthreads();
  }

  // epilogue: lane holds C[m = lane&15][n-quad = (lane>>4)*4 + reg]
  #pragma unroll
  for (int mi=0; mi<4; ++mi) {
    int m = m0 + mi*16 + lrow;
    #pragma unroll
    for (int ni=0; ni<5; ++ni) {
      int nb = wn0 + ni*16 + lk*4;
      float4 o = {acc[mi][ni][0], acc[mi][ni][1], acc[mi][ni][2], acc[mi][ni][3]};
      *(float4*)(y + (size_t)m*N_ + nb) = o;
    }
  }
}

// ============================================================
// route_step: one routing sweep for 16 nodes of one batch b (f32 y).
// y staged via global_load_lds; y reads in phase 1 AND phase 2 are
// same-address broadcasts across 16 lanes.
// ============================================================
__global__ __launch_bounds__(256) void route_step(const float* __restrict__ y,
                                                  const float* __restrict__ alpha,
                                                  const float* __restrict__ contrib,
                                                  float* __restrict__ logits,
                                                  const float* __restrict__ vin,
                                                  float* __restrict__ s_part,
                                                  int mode) {
  __shared__ __align__(16) float sh_y[16*640];      // 40 KB [node][k*128+o]
  __shared__ __align__(16) float sh_v[16*132];      //  8.4 KB [cap][o] pad 132
  __shared__ __align__(16) float sh_alpha[16*16*5]; //  5.1 KB [node][cap][k]
  __shared__ float sh_logit[16][16];
  __shared__ float sh_cw[16][16];

  const int t  = threadIdx.x;
  const int ch = blockIdx.x;   // 0..31
  const int b  = blockIdx.y;   // 0..31
  const int n0 = ch*16;

  // ---- stage y: 16 nodes x 640 f32 = 40 KB contiguous, async 10/thread ----
  const float* ybase = y + ((size_t)(b*NODES_ + n0))*KW_*OUT_;
  #pragma unroll
  for (int q=0; q<10; ++q) {
    int d0 = q*256 + (t & ~63);           // wave-uniform chunk base
    async_load16(ybase + (size_t)(d0 + (t & 63))*4, &sh_y[d0*4]);
  }
  // ---- stage alpha: 320 float4 strided over 256 threads ----
  const float* abase = alpha + (size_t)n0*CAPS_*KW_;
  for (int i = t; i < 320; i += 256) {
    float4 av = *(const float4*)(abase + i*4);
    *(float4*)&sh_alpha[i*4] = av;
  }
  if (mode >= 1) {
    const float* vbase = vin + (size_t)b*CAPS_*OUT_;
    #pragma unroll
    for (int q=0; q<2; ++q) {
      int flat = (t + q*256)*4;
      int c = flat >> 7, o = flat & 127;
      float4 vv = *(const float4*)(vbase + flat);
      *(float4*)&sh_v[c*132 + o] = vv;
    }
    int node = t & 15, cap = t >> 4;
    sh_logit[node][cap] = logits[((size_t)b*CAPS_ + cap)*NODES_ + n0 + node];
  } else {
    int node = t & 15, cap = t >> 4;
    float cv = contrib[(size_t)b*NODES_ + n0 + node];
    sh_logit[node][cap] = cv;
    logits[((size_t)b*CAPS_ + cap)*NODES_ + n0 + node] = cv;
  }
  __syncthreads();

  if (mode >= 1) {
    // ---- phase 1: a[node][cap] = sum_o u*v  (y reads broadcast over caps) ----
    int node = t >> 4, cap = t & 15;
    const float* al = &sh_alpha[(node*16+cap)*5];
    float a0=al[0],a1=al[1],a2=al[2],a3=al[3],a4=al[4];
    const float* yb = &sh_y[node*640];
    const float* vb = &sh_v[cap*132];
    float accd = 0.f;
    #pragma unroll 4
    for (int o=0; o<128; o+=4) {
      float4 y0 = *(const float4*)(yb + 0*128 + o);
      float4 y1 = *(const float4*)(yb + 1*128 + o);
      float4 y2 = *(const float4*)(yb + 2*128 + o);
      float4 y3 = *(const float4*)(yb + 3*128 + o);
      float4 y4 = *(const float4*)(yb + 4*128 + o);
      float4 vv = *(const float4*)(vb + o);
      float ux = a0*y0.x + a1*y1.x + a2*y2.x + a3*y3.x + a4*y4.x;
      float uy = a0*y0.y + a1*y1.y + a2*y2.y + a3*y3.y + a4*y4.y;
      float uz = a0*y0.z + a1*y1.z + a2*y2.z + a3*y3.z + a4*y4.z;
      float uw = a0*y0.w + a1*y1.w + a2*y2.w + a3*y3.w + a4*y4.w;
      accd += ux*vv.x + uy*vv.y + uz*vv.z + uw*vv.w;
    }
    float newl = sh_logit[node][cap] + accd;
    sh_logit[node][cap] = newl;
    logits[((size_t)b*CAPS_ + cap)*NODES_ + n0 + node] = newl;
    __syncthreads();
    // softmax over caps, one thread per node
    if (t < 16) {
      int nd = t;
      float m = -1e30f;
      #pragma unroll
      for (int c=0;c<16;++c) m = fmaxf(m, sh_logit[nd][c]);
      float s = 0.f;
      float e[16];
      #pragma unroll
      for (int c=0;c<16;++c) { e[c] = __expf(sh_logit[nd][c]-m); s += e[c]; }
      float inv = 1.f/s;
      #pragma unroll
      for (int c=0;c<16;++c) sh_cw[nd][c] = e[c]*inv;
    }
  } else {
    int node = t >> 4, cap = t & 15;
    sh_cw[node][cap] = 1.f/16.f;
  }
  __syncthreads();

  // ---- phase 2: s_part[c][o] = sum_node cw*u  (c fast -> y broadcast) ----
  float* spb = s_part + ((size_t)(b*NCH + ch))*CAPS_*OUT_;
  #pragma unroll
  for (int sl=0; sl<2; ++sl) {
    int slot = t + sl*256;
    int c  = slot & 15;
    int o  = (slot >> 4) * 4;   // 0..124
    float4 acc = {0.f,0.f,0.f,0.f};
    #pragma unroll 4
    for (int nd=0; nd<16; ++nd) {
      const float* al = &sh_alpha[(nd*16+c)*5];
      float a0=al[0],a1=al[1],a2=al[2],a3=al[3],a4=al[4];
      const float* yb = &sh_y[nd*640 + o];
      float4 y0 = *(const float4*)(yb);
      float4 y1 = *(const float4*)(yb + 128);
      float4 y2 = *(const float4*)(yb + 256);
      float4 y3 = *(const float4*)(yb + 384);
      float4 y4 = *(const float4*)(yb + 512);
      float cw = sh_cw[nd][c];
      acc.x += cw*(a0*y0.x + a1*y1.x + a2*y2.x + a3*y3.x + a4*y4.x);
      acc.y += cw*(a0*y0.y + a1*y1.y + a2*y2.y + a3*y3.y + a4*y4.y);
      acc.z += cw*(a0*y0.z + a1*y1.z + a2*y2.z + a3*y3.z + a4*y4.z);
      acc.w += cw*(a0*y0.w + a1*y1.w + a2*y2.w + a3*y3.w + a4*y4.w);
    }
    *(float4*)(spb + c*OUT_ + o) = acc;
  }
}

// ============================================================
// squash_k: reduce s_part over chunks, squash, write v (or out)
// ============================================================
__global__ __launch_bounds__(128) void squash_k(const float* __restrict__ s_part,
                                                float* __restrict__ out) {
  const int bc = blockIdx.x;       // b*16+c
  const int o  = threadIdx.x;      // 0..127
  const int b = bc >> 4, c = bc & 15;
  const float* sp = s_part + ((size_t)(b*NCH)*CAPS_ + c)*OUT_ + o;
  float s = 0.f;
  #pragma unroll
  for (int ch=0; ch<NCH; ++ch) s += sp[(size_t)ch*CAPS_*OUT_];
  float ss = s*s;
  #pragma unroll
  for (int off=32; off>0; off>>=1) ss += __shfl_down(ss, off, 64);
  __shared__ float red[2];
  if ((o & 63) == 0) red[o>>6] = ss;
  __syncthreads();
  float sn = red[0] + red[1];
  float scale = (sn/(1.f+sn)) / (sqrtf(sn)+1e-8f);
  out[(size_t)bc*OUT_ + o] = scale*s;
}

// ============================================================
extern "C" void kernel_launch(void* const* d_in, const int* in_sizes, int n_in,
                              void* d_out, int out_size, void* d_ws, size_t ws_size,
                              hipStream_t stream) {
  const float* x       = (const float*)d_in[0];
  const float* contrib = (const float*)d_in[1];
  const float* W       = (const float*)d_in[2];
  const float* alpha   = (const float*)d_in[3];
  float* out = (float*)d_out;
  char*  wsb = (char*)d_ws;

  float* y             = (float*)(wsb + Y_BOFF);
  float* logits        = (float*)(wsb + L_BOFF);
  float* v             = (float*)(wsb + V_BOFF);
  float* s_part        = (float*)(wsb + SP_BOFF);
  // bT hi/lo alias the s_part region (consumed before s_part first written)
  unsigned short* bThi = (unsigned short*)(wsb + SP_BOFF);
  unsigned short* bTlo = (unsigned short*)(wsb + SP_BOFF + BT_SZ);

  conv_w<<<N_, 256, 0, stream>>>(W, bThi, bTlo);
  gemm_fn<<<M_/64, 512, 0, stream>>>(x, bThi, bTlo, y);

  route_step<<<dim3(NCH, B_), 256, 0, stream>>>(y, alpha, contrib, logits, v, s_part, 0);
  squash_k<<<B_*CAPS_, 128, 0, stream>>>(s_part, v);

  for (int it=0; it<3; ++it) {
    route_step<<<dim3(NCH, B_), 256, 0, stream>>>(y, alpha, contrib, logits, v, s_part, 1);
    squash_k<<<B_*CAPS_, 128, 0, stream>>>(s_part, (it==2) ? out : v);
  }
}